// Round 1
// baseline (166.043 us; speedup 1.0000x reference)
//
#include <hip/hip_runtime.h>

// out[b,s,:] = W[:, text[b,s]] + bias + pe[s,:]
// text: int32 [B,S]; W: f32 [D, VOCAB]; bias: f32 [D]; pe: f32 [MAX_LEN, D]
// out: f32 [B,S,D]

#define VOCAB 32000
#define DMODEL 1024
#define S_LEN  2048
#define B_N    4

__global__ __launch_bounds__(256) void embed_pe_kernel(
    const int* __restrict__ text,
    const float* __restrict__ W,
    const float* __restrict__ bias,
    const float* __restrict__ pe,
    float* __restrict__ out)
{
    const int bs = blockIdx.x;              // 0 .. B*S-1
    const int s  = bs & (S_LEN - 1);        // position within sequence
    const int tok = text[bs];               // block-uniform -> scalar load

    const int d4 = threadIdx.x;             // 0..255, each owns 4 dims
    const int d  = d4 << 2;

    const float4 b4 = *reinterpret_cast<const float4*>(bias + d);
    const float4 p4 = *reinterpret_cast<const float4*>(pe + (size_t)s * DMODEL + d);

    const float* wcol = W + (size_t)d * VOCAB + tok;
    float4 o;
    o.x = wcol[0]               + b4.x + p4.x;
    o.y = wcol[(size_t)VOCAB]   + b4.y + p4.y;
    o.z = wcol[(size_t)2*VOCAB] + b4.z + p4.z;
    o.w = wcol[(size_t)3*VOCAB] + b4.w + p4.w;

    *reinterpret_cast<float4*>(out + (size_t)bs * DMODEL + d) = o;
}

extern "C" void kernel_launch(void* const* d_in, const int* in_sizes, int n_in,
                              void* d_out, int out_size, void* d_ws, size_t ws_size,
                              hipStream_t stream) {
    const int*   text = (const int*)d_in[0];
    const float* W    = (const float*)d_in[1];
    const float* bias = (const float*)d_in[2];
    const float* pe   = (const float*)d_in[3];
    float*       out  = (float*)d_out;

    const int n_tok = B_N * S_LEN;          // 8192 blocks, one per (b,s)
    embed_pe_kernel<<<n_tok, 256, 0, stream>>>(text, W, bias, pe, out);
}

// Round 2
// 90.717 us; speedup vs baseline: 1.8303x; 1.8303x over previous
//
#include <hip/hip_runtime.h>

// out[b,s,:] = W[:, text[b,s]] + bias + pe[s,:]
// text: int32 [B,S]; W: f32 [D, VOCAB]; bias: f32 [D]; pe: f32 [MAX_LEN, D]
// out: f32 [B,S,D]
//
// Strategy: counting-sort the 8192 (token, bs) pairs by token, then launch the
// gather with an XCD-aware swizzle so consecutive *sorted* tokens execute on the
// same XCD. W-lines (64B = 16 adjacent vocab entries) carry ~4 token-uses each;
// clustering those uses in one XCD's L2 cuts HBM/L3 fetch ~4x (525 MB -> ~130 MB).

#define VOCAB  32000
#define DMODEL 1024
#define S_LEN  2048
#define B_N    4
#define NTOK   (B_N * S_LEN)   // 8192
#define NXCD   8

// ---- pass 1: histogram of tokens ----
__global__ __launch_bounds__(256) void hist_k(const int* __restrict__ text,
                                              int* __restrict__ hist) {
    int i = blockIdx.x * 256 + threadIdx.x;
    if (i < NTOK) atomicAdd(&hist[text[i]], 1);
}

// ---- pass 2: exclusive scan over 32000 bins (single block) ----
__global__ __launch_bounds__(1024) void scan_k(int* __restrict__ hist) {
    __shared__ int part[1024];
    const int t = threadIdx.x;
    const int base = t * 32;                 // 1024 * 32 = 32768 >= 32000
    int local[32];
    int s = 0;
    #pragma unroll
    for (int j = 0; j < 32; ++j) {
        int idx = base + j;
        int v = (idx < VOCAB) ? hist[idx] : 0;
        local[j] = s;                        // exclusive within chunk
        s += v;
    }
    part[t] = s;
    __syncthreads();
    // Hillis-Steele inclusive scan over the 1024 partials
    for (int off = 1; off < 1024; off <<= 1) {
        int v = (t >= off) ? part[t - off] : 0;
        __syncthreads();
        part[t] += v;
        __syncthreads();
    }
    const int excl = (t == 0) ? 0 : part[t - 1];
    #pragma unroll
    for (int j = 0; j < 32; ++j) {
        int idx = base + j;
        if (idx < VOCAB) hist[idx] = excl + local[j];
    }
}

// ---- pass 3: scatter (token, bs) into sorted order ----
__global__ __launch_bounds__(256) void scatter_k(const int* __restrict__ text,
                                                 int* __restrict__ offs,
                                                 int2* __restrict__ sorted) {
    int i = blockIdx.x * 256 + threadIdx.x;
    if (i < NTOK) {
        int tok = text[i];
        int slot = atomicAdd(&offs[tok], 1);
        sorted[slot] = make_int2(tok, i);
    }
}

// ---- pass 4: gather + bias + pe, XCD-clustered over sorted tokens ----
__global__ __launch_bounds__(256) void gather_k(const int2* __restrict__ sorted,
                                                const float* __restrict__ W,
                                                const float* __restrict__ bias,
                                                const float* __restrict__ pe,
                                                float* __restrict__ out) {
    // blockIdx round-robins XCDs (blk % 8 -> XCD). Remap so XCD x handles the
    // contiguous sorted range [x*1024, (x+1)*1024) in temporal order.
    const int blk = blockIdx.x;
    const int g = ((blk & (NXCD - 1)) << 10) | (blk >> 3);   // 8192 = 8 * 1024

    const int2 p = sorted[g];
    const int tok = p.x;
    const int bs  = p.y;
    const int s   = bs & (S_LEN - 1);

    const int d = threadIdx.x << 2;          // 4 dims per thread

    const float4 b4 = *reinterpret_cast<const float4*>(bias + d);
    const float4 p4 = *reinterpret_cast<const float4*>(pe + (size_t)s * DMODEL + d);

    const float* wcol = W + (size_t)d * VOCAB + tok;
    float4 o;
    o.x = wcol[0]                 + b4.x + p4.x;
    o.y = wcol[(size_t)VOCAB]     + b4.y + p4.y;
    o.z = wcol[(size_t)2 * VOCAB] + b4.z + p4.z;
    o.w = wcol[(size_t)3 * VOCAB] + b4.w + p4.w;

    *reinterpret_cast<float4*>(out + (size_t)bs * DMODEL + d) = o;
}

// ---- fallback (ws too small): direct gather, round-1 kernel ----
__global__ __launch_bounds__(256) void embed_pe_direct(const int* __restrict__ text,
                                                       const float* __restrict__ W,
                                                       const float* __restrict__ bias,
                                                       const float* __restrict__ pe,
                                                       float* __restrict__ out) {
    const int bs = blockIdx.x;
    const int s  = bs & (S_LEN - 1);
    const int tok = text[bs];
    const int d = threadIdx.x << 2;
    const float4 b4 = *reinterpret_cast<const float4*>(bias + d);
    const float4 p4 = *reinterpret_cast<const float4*>(pe + (size_t)s * DMODEL + d);
    const float* wcol = W + (size_t)d * VOCAB + tok;
    float4 o;
    o.x = wcol[0]                 + b4.x + p4.x;
    o.y = wcol[(size_t)VOCAB]     + b4.y + p4.y;
    o.z = wcol[(size_t)2 * VOCAB] + b4.z + p4.z;
    o.w = wcol[(size_t)3 * VOCAB] + b4.w + p4.w;
    *reinterpret_cast<float4*>(out + (size_t)bs * DMODEL + d) = o;
}

extern "C" void kernel_launch(void* const* d_in, const int* in_sizes, int n_in,
                              void* d_out, int out_size, void* d_ws, size_t ws_size,
                              hipStream_t stream) {
    const int*   text = (const int*)d_in[0];
    const float* W    = (const float*)d_in[1];
    const float* bias = (const float*)d_in[2];
    const float* pe   = (const float*)d_in[3];
    float*       out  = (float*)d_out;

    const size_t hist_bytes   = (size_t)VOCAB * sizeof(int);     // 128000 (8-aligned)
    const size_t sorted_bytes = (size_t)NTOK * sizeof(int2);     // 65536
    if (ws_size < hist_bytes + sorted_bytes) {
        embed_pe_direct<<<NTOK, 256, 0, stream>>>(text, W, bias, pe, out);
        return;
    }

    int*  hist   = (int*)d_ws;
    int2* sorted = (int2*)((char*)d_ws + hist_bytes);

    hipMemsetAsync(hist, 0, hist_bytes, stream);
    hist_k   <<<(NTOK + 255) / 256, 256, 0, stream>>>(text, hist);
    scan_k   <<<1, 1024, 0, stream>>>(hist);
    scatter_k<<<(NTOK + 255) / 256, 256, 0, stream>>>(text, hist, sorted);
    gather_k <<<NTOK, 256, 0, stream>>>(sorted, W, bias, pe, out);
}

// Round 3
// 77.183 us; speedup vs baseline: 2.1513x; 1.1753x over previous
//
#include <hip/hip_runtime.h>

// out[b,s,:] = W[:, text[b,s]] + bias + pe[s,:]
// text: int32 [B,S]; W: f32 [D, VOCAB]; bias: f32 [D]; pe: f32 [MAX_LEN, D]
//
// Round 3: counting-sort tokens (as round 2), then gather with lanes varying
// over the SORTED-TOKEN axis so clustered/duplicate tokens coalesce into
// shared 64B lines (~4x fewer memory transactions; round-2 was latency-bound
// at 0.18 lines/cyc/CU with zero coalescing). Tile staged in LDS, written out
// coalesced in a second phase.

#define VOCAB  32000
#define DMODEL 1024
#define S_LEN  2048
#define B_N    4
#define NTOK   (B_N * S_LEN)   // 8192
#define NXCD   8

#define T_CHUNK 16             // sorted tokens per block
#define D_CHUNK 256            // d-entries per block
#define NTCH    (NTOK / T_CHUNK)    // 512
#define NDCH    (DMODEL / D_CHUNK)  // 4
#define NBLK    (NTCH * NDCH)       // 2048
#define LDS_STRIDE 260         // 256 + 4: keeps float4 alignment, breaks bank stride

// ---- pass 1: histogram of tokens ----
__global__ __launch_bounds__(256) void hist_k(const int* __restrict__ text,
                                              int* __restrict__ hist) {
    int i = blockIdx.x * 256 + threadIdx.x;
    if (i < NTOK) atomicAdd(&hist[text[i]], 1);
}

// ---- pass 2: exclusive scan over 32000 bins (single block) ----
__global__ __launch_bounds__(1024) void scan_k(int* __restrict__ hist) {
    __shared__ int part[1024];
    const int t = threadIdx.x;
    const int base = t * 32;
    int local[32];
    int s = 0;
    #pragma unroll
    for (int j = 0; j < 32; ++j) {
        int idx = base + j;
        int v = (idx < VOCAB) ? hist[idx] : 0;
        local[j] = s;
        s += v;
    }
    part[t] = s;
    __syncthreads();
    for (int off = 1; off < 1024; off <<= 1) {
        int v = (t >= off) ? part[t - off] : 0;
        __syncthreads();
        part[t] += v;
        __syncthreads();
    }
    const int excl = (t == 0) ? 0 : part[t - 1];
    #pragma unroll
    for (int j = 0; j < 32; ++j) {
        int idx = base + j;
        if (idx < VOCAB) hist[idx] = excl + local[j];
    }
}

// ---- pass 3: scatter (token, bs) into sorted order ----
__global__ __launch_bounds__(256) void scatter_k(const int* __restrict__ text,
                                                 int* __restrict__ offs,
                                                 int2* __restrict__ sorted) {
    int i = blockIdx.x * 256 + threadIdx.x;
    if (i < NTOK) {
        int tok = text[i];
        int slot = atomicAdd(&offs[tok], 1);
        sorted[slot] = make_int2(tok, i);
    }
}

// ---- pass 4: token-coalesced gather via LDS tile, coalesced write-out ----
__global__ __launch_bounds__(256) void gather_k(const int2* __restrict__ sorted,
                                                const float* __restrict__ W,
                                                const float* __restrict__ bias,
                                                const float* __restrict__ pe,
                                                float* __restrict__ out) {
    __shared__ float lds[T_CHUNK * LDS_STRIDE];   // 16.6 KB

    // XCD swizzle: blk%8 -> XCD; give each XCD a contiguous sorted-token range.
    const int phys = blockIdx.x;
    const int gw = ((phys & (NXCD - 1)) << 8) | (phys >> 3);  // 2048 = 8*256
    const int tchunk = gw >> 2;          // /NDCH
    const int dchunk = gw & (NDCH - 1);

    const int tid = threadIdx.x;
    const int tbase = tchunk * T_CHUNK;
    const int dbase = dchunk * D_CHUNK;

    // ---- phase 1: gather W into LDS, lanes over sorted tokens ----
    {
        const int tl = tid & (T_CHUNK - 1);   // token lane 0..15
        const int dg = tid >> 4;              // d-group 0..15 (16 d each)
        const int tok = sorted[tbase + tl].x;
        const float* wp = W + (size_t)(dbase + dg * 16) * VOCAB + tok;
        float* lp = lds + tl * LDS_STRIDE + dg * 16;
        #pragma unroll
        for (int i = 0; i < 16; ++i) {
            lp[i] = wp[(size_t)i * VOCAB];
        }
    }
    __syncthreads();

    // ---- phase 2: add bias + pe, coalesced float4 store ----
    {
        const int lane = tid & 63;            // 64 lanes cover 256 floats
        const int rsub = tid >> 6;            // 4 rows at a time
        const int d = dbase + lane * 4;
        const float4 b4 = *reinterpret_cast<const float4*>(bias + d);
        #pragma unroll
        for (int rr = 0; rr < T_CHUNK / 4; ++rr) {
            const int row = rr * 4 + rsub;
            const int2 p = sorted[tbase + row];
            const int bs = p.y;
            const int s  = bs & (S_LEN - 1);
            float4 v = *reinterpret_cast<float4*>(lds + row * LDS_STRIDE + lane * 4);
            const float4 p4 = *reinterpret_cast<const float4*>(pe + (size_t)s * DMODEL + d);
            v.x += b4.x + p4.x;
            v.y += b4.y + p4.y;
            v.z += b4.z + p4.z;
            v.w += b4.w + p4.w;
            *reinterpret_cast<float4*>(out + (size_t)bs * DMODEL + d) = v;
        }
    }
}

// ---- fallback (ws too small): direct gather ----
__global__ __launch_bounds__(256) void embed_pe_direct(const int* __restrict__ text,
                                                       const float* __restrict__ W,
                                                       const float* __restrict__ bias,
                                                       const float* __restrict__ pe,
                                                       float* __restrict__ out) {
    const int bs = blockIdx.x;
    const int s  = bs & (S_LEN - 1);
    const int tok = text[bs];
    const int d = threadIdx.x << 2;
    const float4 b4 = *reinterpret_cast<const float4*>(bias + d);
    const float4 p4 = *reinterpret_cast<const float4*>(pe + (size_t)s * DMODEL + d);
    const float* wcol = W + (size_t)d * VOCAB + tok;
    float4 o;
    o.x = wcol[0]                 + b4.x + p4.x;
    o.y = wcol[(size_t)VOCAB]     + b4.y + p4.y;
    o.z = wcol[(size_t)2 * VOCAB] + b4.z + p4.z;
    o.w = wcol[(size_t)3 * VOCAB] + b4.w + p4.w;
    *reinterpret_cast<float4*>(out + (size_t)bs * DMODEL + d) = o;
}

extern "C" void kernel_launch(void* const* d_in, const int* in_sizes, int n_in,
                              void* d_out, int out_size, void* d_ws, size_t ws_size,
                              hipStream_t stream) {
    const int*   text = (const int*)d_in[0];
    const float* W    = (const float*)d_in[1];
    const float* bias = (const float*)d_in[2];
    const float* pe   = (const float*)d_in[3];
    float*       out  = (float*)d_out;

    const size_t hist_bytes   = (size_t)VOCAB * sizeof(int);
    const size_t sorted_bytes = (size_t)NTOK * sizeof(int2);
    if (ws_size < hist_bytes + sorted_bytes) {
        embed_pe_direct<<<NTOK, 256, 0, stream>>>(text, W, bias, pe, out);
        return;
    }

    int*  hist   = (int*)d_ws;
    int2* sorted = (int2*)((char*)d_ws + hist_bytes);

    hipMemsetAsync(hist, 0, hist_bytes, stream);
    hist_k   <<<(NTOK + 255) / 256, 256, 0, stream>>>(text, hist);
    scan_k   <<<1, 1024, 0, stream>>>(hist);
    scatter_k<<<(NTOK + 255) / 256, 256, 0, stream>>>(text, hist, sorted);
    gather_k <<<NBLK, 256, 0, stream>>>(sorted, W, bias, pe, out);
}